// Round 11
// baseline (4527.549 us; speedup 1.0000x reference)
//
#include <hip/hip_runtime.h>
#include <stdint.h>

// BiLSTM B=32 T=2048 D=256 H=256 (gates i,f,g,o; c = f + c + i*g; h = o + tanh(c))
// R11: two same-dir chains per WG, half-step out of phase, so one chain's gates
//   (VALU+LDS latency) hides under the other chain's MFMA block.
//   16 WGs = (dir d, batch-group pg of 4). Chain A = batch {4pg,4pg+1},
//   chain B = {4pg+2,4pg+3}. 512 thr = 8 waves (2/SIMD). Wave w owns 32 hidden
//   cols (8 gate-tiles); aU (i8) shared by both chains = 128 VGPR.
//   Iter: MFMA_A(t) || gates_B(t) -> bar -> MFMA_B(t+1) || gates_A(t) -> bar.
//   i8 math identical to R9/R10 -> same absmax.

#define TT 2048

typedef __attribute__((ext_vector_type(8))) short  short8;
typedef __attribute__((ext_vector_type(8))) __bf16 bf16x8;
typedef __attribute__((ext_vector_type(4))) float  f32x4;
typedef __attribute__((ext_vector_type(4))) int    i32x4;

#define XW_BYTES    (2ull*TT*32*1024*2)     // 256 MiB bf16 [d][t][gb][hcol][gate]
#define STAGE_BYTES (2ull*TT*32*256*2)      // 64 MiB  bf16 [d][t][gb][hcol]

__device__ __forceinline__ unsigned short f2bf(float x){
  uint32_t u = __float_as_uint(x);
  return (unsigned short)((u + 0x7fffu + ((u>>16)&1u)) >> 16);
}
__device__ __forceinline__ float bf2f(unsigned short h){
  return __uint_as_float(((uint32_t)h)<<16);
}

// ---------------- Phase 1: x@W + b -> xw (bf16, [d][t][gb][hcol][gate]) --------
__global__ __launch_bounds__(512, 2)
void k_xw(const float* __restrict__ x, const float* __restrict__ Wf,
          const float* __restrict__ Wb, const float* __restrict__ bf,
          const float* __restrict__ bb, uint16_t* __restrict__ xw)
{
  __shared__ uint16_t wt[1024*32];  // 64 KiB
  const int bid = blockIdx.x;
  const int d   = bid >> 10;
  const int t0  = (bid & 1023) * 2;
  const float* __restrict__ W    = d ? Wb : Wf;
  const float* __restrict__ bias = d ? bb : bf;
  const int tid  = threadIdx.x;
  const int lane = tid & 63;
  const int wv   = tid >> 6;
  const int mt   = wv >> 1;
  const int nh   = wv & 1;
  const int l15  = lane & 15, lg = lane >> 4;

  f32x4 acc[32];
#pragma unroll
  for (int i=0;i<32;i++) acc[i] = (f32x4){0.f,0.f,0.f,0.f};

  const int arow = mt*16 + l15;
  const int ab   = arow & 31;
  const int atl  = arow >> 5;
  const float* __restrict__ xrow = x + ((size_t)ab*TT + (t0+atl))*256;

  for (int kc = 0; kc < 8; ++kc) {
    const int k0 = kc*32;
    __syncthreads();
#pragma unroll
    for (int cc=0; cc<2; ++cc){
      const int c = tid + cc*512;
      union { unsigned short s[32]; short8 v8[4]; } u;
#pragma unroll
      for (int j=0;j<32;j++) u.s[j] = f2bf(W[(size_t)(k0+j)*1024 + c]);
      short8* dst = (short8*)&wt[c*32];
#pragma unroll
      for (int o=0;o<4;o++) dst[o ^ (c&3)] = u.v8[o];
    }
    __syncthreads();
    union { unsigned short s[8]; short8 v; } af;
    {
      const float4 a0 = *(const float4*)&xrow[k0 + lg*8];
      const float4 a1 = *(const float4*)&xrow[k0 + lg*8 + 4];
      af.s[0]=f2bf(a0.x); af.s[1]=f2bf(a0.y); af.s[2]=f2bf(a0.z); af.s[3]=f2bf(a0.w);
      af.s[4]=f2bf(a1.x); af.s[5]=f2bf(a1.y); af.s[6]=f2bf(a1.z); af.s[7]=f2bf(a1.w);
    }
#pragma unroll
    for (int nt=0; nt<32; ++nt){
      const int ct = nh*512 + nt*16 + l15;
      short8 bfr = *(const short8*)&wt[ct*32 + ((lg ^ (ct&3))<<3)];
      acc[nt] = __builtin_amdgcn_mfma_f32_16x16x32_bf16(
        __builtin_bit_cast(bf16x8, af.v), __builtin_bit_cast(bf16x8, bfr), acc[nt], 0,0,0);
    }
  }
#pragma unroll
  for (int nt=0; nt<32; ++nt){
    const int c = nh*512 + nt*16 + l15;
    const int gate = c >> 8, hc = c & 255;
    const float bv = bias[c];
#pragma unroll
    for (int q=0;q<4;q++){
      const int row = mt*16 + lg*4 + q;
      const int b = row & 31, tl = row >> 5;
      xw[((size_t)(d*TT + t0 + tl)*32 + b)*1024 + hc*4 + gate] = f2bf(acc[nt][q] + bv);
    }
  }
}

// ---------------- Phase 2: recurrence, 16 WGs x 512 thr, 2 chains/WG ----------
__global__ __launch_bounds__(512, 1)
void k_rec(const float* __restrict__ Uf, const float* __restrict__ Ub,
           const uint16_t* __restrict__ xw, uint16_t* __restrict__ stage,
           float* __restrict__ out)
{
  const int bid = blockIdx.x;           // 0..15
  const int d   = bid >> 3;
  const int pg  = bid & 7;              // batch group of 4
  const int tid  = threadIdx.x;
  const int lane = tid & 63;
  const int w    = tid >> 6;            // wave 0..7, owns hid cols [32w,32w+32)
  const int l15  = lane & 15, lg = lane >> 4;

  const float* __restrict__ U = d ? Ub : Uf;

  __shared__ i32x4 preA[512];                             // [n][256] q-packed, 8KB
  __shared__ i32x4 preB[512];
  __shared__ __align__(16) unsigned char hA[2][512];      // h i8 dbuf [n][256]
  __shared__ __align__(16) unsigned char hB[2][512];

  // ---- aU[i][m], i = q*2+jt; A elem j: U[k = m*64+lg*16+j][g = q*256+w*32+jt*16+l15]
  i32x4 aU[8][4];
#pragma unroll
  for (int q=0;q<4;q++)
#pragma unroll
    for (int jt=0;jt<2;jt++){
      const int g = q*256 + w*32 + jt*16 + l15;
#pragma unroll
      for (int m=0;m<4;m++){
        uint32_t rg[4] = {0,0,0,0};
#pragma unroll
        for (int jj=0;jj<16;jj++){
          const int k = m*64 + lg*16 + jj;
          float u = U[(size_t)k*1024 + g];
          int v = __float2int_rn(u * 2032.0f);            // 127/0.0625
          v = v > 127 ? 127 : (v < -127 ? -127 : v);
          rg[jj>>2] |= (uint32_t)(v & 255) << ((jj&3)*8);
        }
        aU[q*2+jt][m] = (i32x4){(int)rg[0],(int)rg[1],(int)rg[2],(int)rg[3]};
      }
    }

  // ---- init: h_A(-1)=0; pre_B(0) = U*0 = 0 ----
  preB[tid] = (i32x4){0,0,0,0};
  if (tid < 64) ((i32x4*)hA)[tid] = (i32x4){0,0,0,0};
  __syncthreads();

  // ---- per-thread gates cell: (n = tid&1, hc = tid>>1) ----
  const int cn = tid & 1;
  const int hc = tid >> 1;              // 0..255
  const int gbA = pg*4 + cn;
  const int gbB = pg*4 + 2 + cn;
  const float DQ = 1.0f / (2032.0f * 63.5f);
  const int hwr = cn*256 + (hc ^ (cn<<6));   // swizzled h write byte offset

  const long xstep = (d ? -1 : 1) * (long)(32*1024);
  const long sstep = (d ? -1 : 1) * (long)(32*256);
  const int tg0 = d ? TT-1 : 0;
  const uint16_t* pAx = xw + ((size_t)(d*TT + tg0)*32 + gbA)*1024 + hc*4;
  const uint16_t* pBx = xw + ((size_t)(d*TT + tg0)*32 + gbB)*1024 + hc*4;
  uint16_t* pAs = stage + ((size_t)(d*TT + tg0)*32 + gbA)*256 + hc;
  uint16_t* pBs = stage + ((size_t)(d*TT + tg0)*32 + gbB)*256 + hc;
  uint64_t gwA0 = *(const uint64_t*)pAx; pAx += xstep;
  uint64_t gwA1 = *(const uint64_t*)pAx; pAx += xstep;
  uint64_t gwB0 = *(const uint64_t*)pBx; pBx += xstep;
  uint64_t gwB1 = *(const uint64_t*)pBx; pBx += xstep;

  float csA = 0.f, csB = 0.f, hAv = 0.f, hBv = 0.f;

  for (int t = 0; t < TT; ++t) {
    const int p = t & 1;

    // ---- ph1: MFMA_A(t)  (reads hA[p]) ----
    i32x4 accA[8];
#pragma unroll
    for (int i=0;i<8;i++) accA[i] = (i32x4){0,0,0,0};
    {
      const unsigned char* ha = &hA[p][0];
      const int nb = l15 & 1;
#pragma unroll
      for (int m=0;m<4;m++){
        i32x4 hf = *(const i32x4*)(ha + nb*256 + ((m*64 + lg*16) ^ (nb<<6)));
#pragma unroll
        for (int i=0;i<8;i++)
          accA[i] = __builtin_amdgcn_mfma_i32_16x16x64_i8(aU[i][m], hf, accA[i], 0,0,0);
      }
    }

    // ---- ph2: gates_B(t)  (preB ready; independent of accA -> overlaps ph1) ----
    {
      i32x4 pv = preB[cn*256 + hc];
      float pr[4];
#pragma unroll
      for (int q=0;q<4;q++)
        pr[q] = (float)pv[q]*DQ + bf2f((unsigned short)(gwB0 >> (q*16)));
      float si = __builtin_amdgcn_rcpf(1.0f + __expf(-pr[0]));
      float sf = __builtin_amdgcn_rcpf(1.0f + __expf(-pr[1]));
      float sg = __builtin_amdgcn_rcpf(1.0f + __expf(-pr[2]));
      float so = __builtin_amdgcn_rcpf(1.0f + __expf(-pr[3]));
      csB = sf + csB + si*sg;
      float th = 1.0f - 2.0f*__builtin_amdgcn_rcpf(1.0f + __expf(2.0f*csB));
      hBv = so + th;                    // in (0,2)
      int q8 = (int)(hBv * 63.5f + 0.5f); q8 = q8 > 127 ? 127 : q8;
      hB[p^1][hwr] = (unsigned char)q8;
      *pBs = f2bf(hBv); pBs += sstep;
      gwB0 = gwB1;
      gwB1 = *(const uint64_t*)pBx;
      if (t < TT-3) pBx += xstep;
    }

    // ---- ph3: scatter preA; barrier (h_B(t) + preA visible) ----
    if (l15 < 2){
#pragma unroll
      for (int jt=0;jt<2;jt++)
#pragma unroll
        for (int r=0;r<4;r++){
          i32x4 v = (i32x4){accA[jt][r], accA[2+jt][r], accA[4+jt][r], accA[6+jt][r]};
          preA[l15*256 + w*32 + jt*16 + lg*4 + r] = v;
        }
    }
    asm volatile("s_waitcnt lgkmcnt(0)" ::: "memory");
    __builtin_amdgcn_sched_barrier(0);
    __builtin_amdgcn_s_barrier();
    __builtin_amdgcn_sched_barrier(0);

    // ---- ph4: MFMA_B(t+1)  (reads hB[p^1]) ----
    i32x4 accB[8];
#pragma unroll
    for (int i=0;i<8;i++) accB[i] = (i32x4){0,0,0,0};
    {
      const unsigned char* hb = &hB[p^1][0];
      const int nb = l15 & 1;
#pragma unroll
      for (int m=0;m<4;m++){
        i32x4 hf = *(const i32x4*)(hb + nb*256 + ((m*64 + lg*16) ^ (nb<<6)));
#pragma unroll
        for (int i=0;i<8;i++)
          accB[i] = __builtin_amdgcn_mfma_i32_16x16x64_i8(aU[i][m], hf, accB[i], 0,0,0);
      }
    }

    // ---- ph5: gates_A(t)  (preA from ph3; overlaps ph4) ----
    {
      i32x4 pv = preA[cn*256 + hc];
      float pr[4];
#pragma unroll
      for (int q=0;q<4;q++)
        pr[q] = (float)pv[q]*DQ + bf2f((unsigned short)(gwA0 >> (q*16)));
      float si = __builtin_amdgcn_rcpf(1.0f + __expf(-pr[0]));
      float sf = __builtin_amdgcn_rcpf(1.0f + __expf(-pr[1]));
      float sg = __builtin_amdgcn_rcpf(1.0f + __expf(-pr[2]));
      float so = __builtin_amdgcn_rcpf(1.0f + __expf(-pr[3]));
      csA = sf + csA + si*sg;
      float th = 1.0f - 2.0f*__builtin_amdgcn_rcpf(1.0f + __expf(2.0f*csA));
      hAv = so + th;
      int q8 = (int)(hAv * 63.5f + 0.5f); q8 = q8 > 127 ? 127 : q8;
      hA[p^1][hwr] = (unsigned char)q8;
      *pAs = f2bf(hAv); pAs += sstep;
      gwA0 = gwA1;
      gwA1 = *(const uint64_t*)pAx;
      if (t < TT-3) pAx += xstep;
    }

    // ---- ph6: scatter preB(t+1); barrier (h_A(t) + preB visible) ----
    if (l15 < 2){
#pragma unroll
      for (int jt=0;jt<2;jt++)
#pragma unroll
        for (int r=0;r<4;r++){
          i32x4 v = (i32x4){accB[jt][r], accB[2+jt][r], accB[4+jt][r], accB[6+jt][r]};
          preB[l15*256 + w*32 + jt*16 + lg*4 + r] = v;
        }
    }
    asm volatile("s_waitcnt lgkmcnt(0)" ::: "memory");
    __builtin_amdgcn_sched_barrier(0);
    __builtin_amdgcn_s_barrier();
    __builtin_amdgcn_sched_barrier(0);
  }

  // ---- y_t (final h, f32) ----
  out[(size_t)gbA*512 + d*256 + hc] = hAv;
  out[(size_t)gbB*512 + d*256 + hc] = hBv;
}

// ---------------- Phase 3: stage -> y_net expand ----------------
__global__ __launch_bounds__(256)
void k_out(const uint16_t* __restrict__ stage, float* __restrict__ y_net)
{
  const int blk = blockIdx.x;
  const int b = blk >> 11;
  const int t = blk & 2047;
  const int tid = threadIdx.x;
  const uint16_t v0 = stage[((size_t)(0*TT + t)*32 + b)*256 + tid];
  const uint16_t v1 = stage[((size_t)(1*TT + t)*32 + b)*256 + tid];
  float* o = y_net + ((size_t)b*TT + t)*512;
  o[tid]       = bf2f(v0);
  o[tid + 256] = bf2f(v1);
}

extern "C" void kernel_launch(void* const* d_in, const int* in_sizes, int n_in,
                              void* d_out, int out_size, void* d_ws, size_t ws_size,
                              hipStream_t stream)
{
  const float* x  = (const float*)d_in[0];
  const float* Wf = (const float*)d_in[1];
  const float* Uf = (const float*)d_in[2];
  const float* bf = (const float*)d_in[3];
  const float* Wb = (const float*)d_in[4];
  const float* Ub = (const float*)d_in[5];
  const float* bb = (const float*)d_in[6];
  float* out = (float*)d_out;
  uint8_t* ws = (uint8_t*)d_ws;
  uint16_t* xw    = (uint16_t*)ws;
  uint16_t* stage = (uint16_t*)(ws + XW_BYTES);

  k_xw <<<dim3(2048),    dim3(512), 0, stream>>>(x, Wf, Wb, bf, bb, xw);
  k_rec<<<dim3(16),      dim3(512), 0, stream>>>(Uf, Ub, xw, stage, out);
  k_out<<<dim3(32*2048), dim3(256), 0, stream>>>(stage, out + 32*512);
}

// Round 12
// 3294.064 us; speedup vs baseline: 1.3745x; 1.3745x over previous
//
#include <hip/hip_runtime.h>
#include <stdint.h>

// BiLSTM B=32 T=2048 D=256 H=256 (gates i,f,g,o; c = f + c + i*g; h = o + tanh(c))
// R12: ONE chain per CU. 64 WGs = (dir d, batch b). 512 thr = 8 waves (2/SIMD).
//   Wave w owns hidden cols [32w,32w+32) for all 4 gates (tiles (q, 2w+hb2)).
//   MFMA per WG-step: 256 x mfma_i32_16x16x64_i8 (the per-chain floor, batch-
//   independent). Gates: 256 cells/WG (1/4 of R10) on lanes<32 of each wave.
//   B operand = single h vector -> ds_read_b128 BROADCAST (conflict-free).
//   Redistribute wave-local (scatter + lgkmcnt(0)); ONE raw s_barrier/step;
//   gw 2-deep in flight; h bytes shfl-packed to dword writes.
//   i8 math identical to R9-R11 -> same absmax.

#define TT 2048

typedef __attribute__((ext_vector_type(8))) short  short8;
typedef __attribute__((ext_vector_type(8))) __bf16 bf16x8;
typedef __attribute__((ext_vector_type(4))) float  f32x4;
typedef __attribute__((ext_vector_type(4))) int    i32x4;

#define XW_BYTES    (2ull*TT*32*1024*2)     // 256 MiB bf16 [d][t][b][hcol][gate]
#define STAGE_BYTES (2ull*TT*32*256*2)      // 64 MiB  bf16 [d][t][b][hcol]

__device__ __forceinline__ unsigned short f2bf(float x){
  uint32_t u = __float_as_uint(x);
  return (unsigned short)((u + 0x7fffu + ((u>>16)&1u)) >> 16);
}
__device__ __forceinline__ float bf2f(unsigned short h){
  return __uint_as_float(((uint32_t)h)<<16);
}

// ---------------- Phase 1: x@W + b -> xw (bf16, [d][t][b][hcol][gate]) --------
__global__ __launch_bounds__(512, 2)
void k_xw(const float* __restrict__ x, const float* __restrict__ Wf,
          const float* __restrict__ Wb, const float* __restrict__ bf,
          const float* __restrict__ bb, uint16_t* __restrict__ xw)
{
  __shared__ uint16_t wt[1024*32];  // 64 KiB
  const int bid = blockIdx.x;
  const int d   = bid >> 10;
  const int t0  = (bid & 1023) * 2;
  const float* __restrict__ W    = d ? Wb : Wf;
  const float* __restrict__ bias = d ? bb : bf;
  const int tid  = threadIdx.x;
  const int lane = tid & 63;
  const int wv   = tid >> 6;
  const int mt   = wv >> 1;
  const int nh   = wv & 1;
  const int l15  = lane & 15, lg = lane >> 4;

  f32x4 acc[32];
#pragma unroll
  for (int i=0;i<32;i++) acc[i] = (f32x4){0.f,0.f,0.f,0.f};

  const int arow = mt*16 + l15;
  const int ab   = arow & 31;
  const int atl  = arow >> 5;
  const float* __restrict__ xrow = x + ((size_t)ab*TT + (t0+atl))*256;

  for (int kc = 0; kc < 8; ++kc) {
    const int k0 = kc*32;
    __syncthreads();
#pragma unroll
    for (int cc=0; cc<2; ++cc){
      const int c = tid + cc*512;
      union { unsigned short s[32]; short8 v8[4]; } u;
#pragma unroll
      for (int j=0;j<32;j++) u.s[j] = f2bf(W[(size_t)(k0+j)*1024 + c]);
      short8* dst = (short8*)&wt[c*32];
#pragma unroll
      for (int o=0;o<4;o++) dst[o ^ (c&3)] = u.v8[o];
    }
    __syncthreads();
    union { unsigned short s[8]; short8 v; } af;
    {
      const float4 a0 = *(const float4*)&xrow[k0 + lg*8];
      const float4 a1 = *(const float4*)&xrow[k0 + lg*8 + 4];
      af.s[0]=f2bf(a0.x); af.s[1]=f2bf(a0.y); af.s[2]=f2bf(a0.z); af.s[3]=f2bf(a0.w);
      af.s[4]=f2bf(a1.x); af.s[5]=f2bf(a1.y); af.s[6]=f2bf(a1.z); af.s[7]=f2bf(a1.w);
    }
#pragma unroll
    for (int nt=0; nt<32; ++nt){
      const int ct = nh*512 + nt*16 + l15;
      short8 bfr = *(const short8*)&wt[ct*32 + ((lg ^ (ct&3))<<3)];
      acc[nt] = __builtin_amdgcn_mfma_f32_16x16x32_bf16(
        __builtin_bit_cast(bf16x8, af.v), __builtin_bit_cast(bf16x8, bfr), acc[nt], 0,0,0);
    }
  }
#pragma unroll
  for (int nt=0; nt<32; ++nt){
    const int c = nh*512 + nt*16 + l15;
    const int gate = c >> 8, hc = c & 255;
    const float bv = bias[c];
#pragma unroll
    for (int q=0;q<4;q++){
      const int row = mt*16 + lg*4 + q;
      const int b = row & 31, tl = row >> 5;
      xw[((size_t)(d*TT + t0 + tl)*32 + b)*1024 + hc*4 + gate] = f2bf(acc[nt][q] + bv);
    }
  }
}

// ---------------- Phase 2: recurrence, 64 WGs (d x batch), 1 chain each -------
__global__ __launch_bounds__(512, 2)
void k_rec(const float* __restrict__ Uf, const float* __restrict__ Ub,
           const uint16_t* __restrict__ xw, uint16_t* __restrict__ stage,
           float* __restrict__ out)
{
  const int bid = blockIdx.x;           // 0..63
  const int d   = bid >> 5;
  const int b   = bid & 31;
  const int tid  = threadIdx.x;
  const int lane = tid & 63;
  const int w    = tid >> 6;            // wave 0..7: hidden cols [32w, 32w+32)
  const int l15  = lane & 15, lg = lane >> 4;

  const float* __restrict__ U = d ? Ub : Uf;

  __shared__ i32x4 pre16[256];                          // 4 KB: [hc] -> 4 gates i32
  __shared__ __align__(16) unsigned char hlds[2][256];  // h i8 double buffer

  // ---- aU[q][hb2][m] resident: A elem j -> U[k=m*64+lg*16+j][g=q*256+(2w+hb2)*16+l15]
  i32x4 aU[4][2][4];
#pragma unroll
  for (int q=0;q<4;q++)
#pragma unroll
    for (int hb2=0;hb2<2;hb2++){
      const int g = q*256 + (w*2+hb2)*16 + l15;
#pragma unroll
      for (int m=0;m<4;m++){
        uint32_t rg[4] = {0,0,0,0};
#pragma unroll
        for (int jj=0;jj<16;jj++){
          const int k = m*64 + lg*16 + jj;
          float u = U[(size_t)k*1024 + g];
          int v = __float2int_rn(u * 2032.0f);          // 127/0.0625
          v = v > 127 ? 127 : (v < -127 ? -127 : v);
          rg[jj>>2] |= (uint32_t)(v & 255) << ((jj&3)*8);
        }
        aU[q][hb2][m] = (i32x4){(int)rg[0],(int)rg[1],(int)rg[2],(int)rg[3]};
      }
    }

  if (tid < 128) ((uint32_t*)hlds)[tid] = 0u;   // zero both h buffers (512 B)
  __syncthreads();

  const bool gl = (lane < 32);
  const int hc  = w*32 + (lane & 31);   // this lane's cell (gates lanes only)
  const float DQ = 1.0f / (2032.0f * 63.5f);

  const long xstep = (d ? -1 : 1) * (long)(32*1024);
  const long sstep = (d ? -1 : 1) * (long)(32*256);
  const int tg0 = d ? TT-1 : 0;
  const uint16_t* px = xw + ((size_t)(d*TT + tg0)*32 + b)*1024 + hc*4;
  uint16_t* ps = stage + ((size_t)(d*TT + tg0)*32 + b)*256 + hc;

  uint64_t gw0 = 0, gw1 = 0;
  if (gl) {
    gw0 = *(const uint64_t*)px; px += xstep;
    gw1 = *(const uint64_t*)px; px += xstep;
  }

  float cs = 0.f, hv = 0.f;

  for (int t = 0; t < TT; ++t) {
    const int p = t & 1;

    // ---- B-frags: broadcast reads of the single h vector ----
    i32x4 hf[4];
#pragma unroll
    for (int m=0;m<4;m++)
      hf[m] = *(const i32x4*)&hlds[p][m*64 + lg*16];

    // ---- MFMA: 32 insts (8 tiles x 4 K-frags), wave-local tiles ----
    i32x4 acc[8];
#pragma unroll
    for (int i=0;i<8;i++) acc[i] = (i32x4){0,0,0,0};
#pragma unroll
    for (int m=0;m<4;m++)
#pragma unroll
      for (int q=0;q<4;q++)
#pragma unroll
        for (int hb2=0;hb2<2;hb2++)
          acc[q*2+hb2] = __builtin_amdgcn_mfma_i32_16x16x64_i8(
            aU[q][hb2][m], hf[m], acc[q*2+hb2], 0,0,0);

    // ---- wave-local scatter: valid col l15==0; row = lg*4+r ----
    if (l15 == 0){
#pragma unroll
      for (int hb2=0;hb2<2;hb2++)
#pragma unroll
        for (int r=0;r<4;r++){
          i32x4 v = (i32x4){acc[0*2+hb2][r], acc[1*2+hb2][r],
                            acc[2*2+hb2][r], acc[3*2+hb2][r]};
          pre16[w*32 + hb2*16 + lg*4 + r] = v;
        }
    }
    asm volatile("s_waitcnt lgkmcnt(0)" ::: "memory");
    __builtin_amdgcn_sched_barrier(0);

    // ---- gates: lanes<32, 1 cell each ----
    uint32_t hq = 0;
    if (gl) {
      i32x4 pv = pre16[hc];
      const uint64_t gwc = p ? gw1 : gw0;
      float pr[4];
#pragma unroll
      for (int q=0;q<4;q++)
        pr[q] = fmaf((float)pv[q], DQ, bf2f((unsigned short)(gwc >> (q*16))));
      float si = __builtin_amdgcn_rcpf(1.0f + __expf(-pr[0]));
      float sf = __builtin_amdgcn_rcpf(1.0f + __expf(-pr[1]));
      float sg = __builtin_amdgcn_rcpf(1.0f + __expf(-pr[2]));
      float so = __builtin_amdgcn_rcpf(1.0f + __expf(-pr[3]));
      cs = sf + cs + si*sg;
      float th = 1.0f - 2.0f*__builtin_amdgcn_rcpf(1.0f + __expf(2.0f*cs));
      hv = so + th;                     // in (0,2)
      int q8 = (int)(hv * 63.5f + 0.5f); q8 = q8 > 127 ? 127 : q8;
      hq = (uint32_t)q8;
      // stage (bf16, fire-and-forget; not drained by raw barrier)
      *ps = f2bf(hv); ps += sstep;
      // gw prefetch for t+2 (stays in flight)
      if (p) gw1 = *(const uint64_t*)px; else gw0 = *(const uint64_t*)px;
      if (t < TT-3) px += xstep;
    }

    // ---- h bytes: shfl-pack 4 cells -> one dword write (conflict-free) ----
    uint32_t b1 = __shfl(hq, lane+1);
    uint32_t b2 = __shfl(hq, lane+2);
    uint32_t b3 = __shfl(hq, lane+3);
    if (gl && (lane & 3) == 0)
      *(uint32_t*)&hlds[p^1][hc] = hq | (b1<<8) | (b2<<16) | (b3<<24);

    // ---- step boundary: LDS visibility + raw barrier (NO vmcnt drain) ----
    asm volatile("s_waitcnt lgkmcnt(0)" ::: "memory");
    __builtin_amdgcn_sched_barrier(0);
    __builtin_amdgcn_s_barrier();
    __builtin_amdgcn_sched_barrier(0);
  }

  // ---- y_t (final h, f32) ----
  if (gl) out[(size_t)b*512 + d*256 + hc] = hv;
}

// ---------------- Phase 3: stage -> y_net expand ----------------
__global__ __launch_bounds__(256)
void k_out(const uint16_t* __restrict__ stage, float* __restrict__ y_net)
{
  const int blk = blockIdx.x;
  const int b = blk >> 11;
  const int t = blk & 2047;
  const int tid = threadIdx.x;
  const uint16_t v0 = stage[((size_t)(0*TT + t)*32 + b)*256 + tid];
  const uint16_t v1 = stage[((size_t)(1*TT + t)*32 + b)*256 + tid];
  float* o = y_net + ((size_t)b*TT + t)*512;
  o[tid]       = bf2f(v0);
  o[tid + 256] = bf2f(v1);
}

extern "C" void kernel_launch(void* const* d_in, const int* in_sizes, int n_in,
                              void* d_out, int out_size, void* d_ws, size_t ws_size,
                              hipStream_t stream)
{
  const float* x  = (const float*)d_in[0];
  const float* Wf = (const float*)d_in[1];
  const float* Uf = (const float*)d_in[2];
  const float* bf = (const float*)d_in[3];
  const float* Wb = (const float*)d_in[4];
  const float* Ub = (const float*)d_in[5];
  const float* bb = (const float*)d_in[6];
  float* out = (float*)d_out;
  uint8_t* ws = (uint8_t*)d_ws;
  uint16_t* xw    = (uint16_t*)ws;
  uint16_t* stage = (uint16_t*)(ws + XW_BYTES);

  k_xw <<<dim3(2048),    dim3(512), 0, stream>>>(x, Wf, Wb, bf, bb, xw);
  k_rec<<<dim3(64),      dim3(512), 0, stream>>>(Uf, Ub, xw, stage, out);
  k_out<<<dim3(32*2048), dim3(256), 0, stream>>>(stage, out + 32*512);
}